// Round 6
// baseline (490.125 us; speedup 1.0000x reference)
//
#include <hip/hip_runtime.h>

// Problem constants
static constexpr int BB = 4;
static constexpr int SS = 4096;
static constexpr int DD = 1024;
static constexpr int HH = 8;
static constexpr int HD = 128;     // FFT length
static constexpr int CS = 32;      // scan chunk size (positions per block)
static constexpr int NCHUNK = SS / CS;   // 128
static constexpr int MROWS = BB * SS;    // 16384

typedef __attribute__((ext_vector_type(8))) short bfrag;      // 8 bf16 (4 VGPRs)
typedef __attribute__((ext_vector_type(16))) float floatx16;  // 32x32 MFMA acc

// ---------------------------------------------------------------------------
// bf16 helpers
// ---------------------------------------------------------------------------
__device__ __forceinline__ float bf2f(unsigned int u) {   // low 16 bits = bf16
    return __uint_as_float((u & 0xFFFFu) << 16);
}
__device__ __forceinline__ unsigned short f2bf(float f) {  // RNE
    unsigned int x = __float_as_uint(f);
    unsigned int r = x + 0x7FFFu + ((x >> 16) & 1u);
    return (unsigned short)(r >> 16);
}
__device__ __forceinline__ unsigned int pack_rne(float a, float b) {
    return ((unsigned int)f2bf(a)) | (((unsigned int)f2bf(b)) << 16);
}

// async global->LDS, 16B per lane; LDS dest = wave-uniform base + lane*16
__device__ __forceinline__ void async_copy16(const void* g, void* l) {
    __builtin_amdgcn_global_load_lds(
        (const __attribute__((address_space(1))) unsigned int*)g,
        (__attribute__((address_space(3))) unsigned int*)l, 16, 0, 0);
}

// ---------------------------------------------------------------------------
// Complex helpers
// ---------------------------------------------------------------------------
struct cpx { float re, im; };

__device__ __forceinline__ cpx cadd(cpx a, cpx b) { return {a.re + b.re, a.im + b.im}; }
__device__ __forceinline__ cpx csub(cpx a, cpx b) { return {a.re - b.re, a.im - b.im}; }
__device__ __forceinline__ cpx cmul(cpx a, cpx b) {
    return { fmaf(a.re, b.re, -a.im * b.im), fmaf(a.re, b.im, a.im * b.re) };
}
__device__ __forceinline__ cpx cmul_cj(cpx a, cpx b) {   // a * conj(b)
    return { fmaf(a.re, b.re, a.im * b.im), fmaf(a.im, b.re, -a.re * b.im) };
}
__device__ __forceinline__ cpx shflx(cpx x, int m) {
    return { __shfl_xor(x.re, m), __shfl_xor(x.im, m) };
}
__device__ __forceinline__ cpx shfl_at(cpx x, int src) {
    return { __shfl(x.re, src), __shfl(x.im, src) };
}

// bin held at (reg r, lane l) is n = 2*rev6(l) + r (bit-reversed DIF output).
// Conjugate pair bin (-n mod 128) stays in the same reg. Pair lane:
//   reg1: l ^ 63;  reg0: rev6((64 - rev6(l)) & 63)
__device__ __forceinline__ int pair_lane_even(int l) {
    int m = (int)(__brev((unsigned)l) >> 26);
    int mp = (64 - m) & 63;
    return (int)(__brev((unsigned)mp) >> 26);
}

__device__ __forceinline__ void make_tw(int lane, cpx tw[7]) {
    const float NEG2PI = -6.28318530717958647692f;
    float a0 = NEG2PI * (float)lane * (1.0f / 128.0f);
    tw[0] = { __cosf(a0), __sinf(a0) };
    int d = 32;
#pragma unroll
    for (int s = 1; s <= 6; ++s) {
        int i = lane & (d - 1);
        float a = NEG2PI * (float)i / (float)(2 * d);
        tw[s] = { __cosf(a), __sinf(a) };
        d >>= 1;
    }
}

// Forward DIF FFT-128 (complex): natural in (x0=pos lane, x1=pos lane+64),
// bit-reversed-permuted out. Unnormalized.
__device__ __forceinline__ void fft128_fwd(cpx& x0, cpx& x1, const cpx tw[7], int lane) {
    cpx a = x0, b = x1;
    x0 = cadd(a, b);
    x1 = cmul(csub(a, b), tw[0]);
    int d = 32;
#pragma unroll
    for (int s = 1; s <= 6; ++s) {
        const bool up = (lane & d) != 0;
        cpx o0 = shflx(x0, d);
        cpx o1 = shflx(x1, d);
        cpx s0 = cadd(x0, o0);
        cpx s1 = cadd(x1, o1);
        cpx d0 = cmul(csub(o0, x0), tw[s]);
        cpx d1 = cmul(csub(o1, x1), tw[s]);
        x0 = up ? d0 : s0;
        x1 = up ? d1 : s1;
        d >>= 1;
    }
}

// Inverse DIT FFT-128: consumes fwd's permuted order, natural order out, /128.
__device__ __forceinline__ void fft128_inv(cpx& x0, cpx& x1, const cpx tw[7], int lane) {
    int d = 1;
#pragma unroll
    for (int s = 6; s >= 1; --s) {
        const bool up = (lane & d) != 0;
        cpx o0 = shflx(x0, d);
        cpx o1 = shflx(x1, d);
        cpx b0 = up ? x0 : o0;
        cpx a0 = up ? o0 : x0;
        cpx b1 = up ? x1 : o1;
        cpx a1 = up ? o1 : x1;
        cpx t0 = cmul_cj(b0, tw[s]);
        cpx t1 = cmul_cj(b1, tw[s]);
        x0 = up ? csub(a0, t0) : cadd(a0, t0);
        x1 = up ? csub(a1, t1) : cadd(a1, t1);
        d <<= 1;
    }
    cpx t = cmul_cj(x1, tw[0]);
    cpx a = x0;
    const float inv = 0.0078125f;
    x0 = { (a.re + t.re) * inv, (a.im + t.im) * inv };
    x1 = { (a.re - t.re) * inv, (a.im - t.im) * inv };
}

// ---------------------------------------------------------------------------
// x fp32 -> bf16 (RNE), 8 elems/thread
// ---------------------------------------------------------------------------
__global__ __launch_bounds__(256) void convert_bf16(const float* __restrict__ X,
                                                    unsigned short* __restrict__ Y)
{
    const size_t i = ((size_t)blockIdx.x * 256 + threadIdx.x) * 8;
    float4 v0 = *reinterpret_cast<const float4*>(X + i);
    float4 v1 = *reinterpret_cast<const float4*>(X + i + 4);
    uint4 p = { pack_rne(v0.x, v0.y), pack_rne(v0.z, v0.w),
                pack_rne(v1.x, v1.y), pack_rne(v1.z, v1.w) };
    *reinterpret_cast<uint4*>(Y + i) = p;
}

// Transpose + RNE bf16: W fp32 [K,N] -> T bf16 [N,K]
__global__ __launch_bounds__(256) void transpose_rn(const float* __restrict__ W,
                                                    unsigned short* __restrict__ T,
                                                    int K, int N)
{
    __shared__ float tile[32][33];
    const int n0 = blockIdx.x * 32, k0 = blockIdx.y * 32;
    const int r = threadIdx.x >> 5, c = threadIdx.x & 31;
#pragma unroll
    for (int i = 0; i < 4; ++i)
        tile[r + 8 * i][c] = W[(size_t)(k0 + r + 8 * i) * N + n0 + c];
    __syncthreads();
#pragma unroll
    for (int i = 0; i < 4; ++i) {
        float v = tile[c][r + 8 * i];
        T[(size_t)(n0 + r + 8 * i) * K + k0 + c] = f2bf(v);
    }
}

// ---------------------------------------------------------------------------
// bf16 GEMM, 32x32x16 MFMA, BK=64: C = A[M,K] * Bt[N,K]^T.
// 128x128 tile, 256 threads, 4 waves each 64x64 via 2x2 of 32x32x16.
// PANEL: C written as column-panels [n0/128][M][128] (row stride 128);
// else standard row-major [M][N].
// ---------------------------------------------------------------------------
template <typename OutT, bool PANEL>
__global__ __launch_bounds__(256) void gemm_bt32(const unsigned short* __restrict__ A,
                                                 const unsigned short* __restrict__ Bt,
                                                 OutT* __restrict__ C,
                                                 int M, int N, int K)
{
    __shared__ __align__(16) unsigned short As[128 * 64];   // 16 KB
    __shared__ __align__(16) unsigned short Bs[128 * 64];   // 16 KB
    const int tid = threadIdx.x, lane = tid & 63, w = tid >> 6;
    const int wr = w >> 1, wc = w & 1;
    const int m0 = blockIdx.y * 128, n0 = blockIdx.x * 128;

    floatx16 acc[2][2];
#pragma unroll
    for (int i = 0; i < 2; ++i)
#pragma unroll
        for (int j = 0; j < 2; ++j)
#pragma unroll
            for (int r = 0; r < 16; ++r) acc[i][j][r] = 0.f;

    // staging: 16 segments of 8 rows x 64 cols (1 KB) per matrix;
    // wave w stages segments 4w..4w+3. lane -> row 8sg+(l>>3), col (l&7)*8.
    const int srow = lane >> 3, scol = (lane & 7) * 8;

    for (int kt = 0; kt < K; kt += 64) {
#pragma unroll
        for (int i = 0; i < 4; ++i) {
            const int sg = 4 * w + i;
            const size_t aoff = (size_t)(m0 + 8 * sg + srow) * K + kt + scol;
            const size_t boff = (size_t)(n0 + 8 * sg + srow) * K + kt + scol;
            async_copy16(A + aoff, &As[sg * 512]);
            async_copy16(Bt + boff, &Bs[sg * 512]);
        }
        __syncthreads();

        const int fr = lane & 31, fk = (lane >> 5) * 8;
#pragma unroll
        for (int kh = 0; kh < 64; kh += 16) {
            bfrag af[2], bf_[2];
#pragma unroll
            for (int t = 0; t < 2; ++t) {
                af[t]  = *reinterpret_cast<const bfrag*>(
                    &As[(64 * wr + 32 * t + fr) * 64 + kh + fk]);
                bf_[t] = *reinterpret_cast<const bfrag*>(
                    &Bs[(64 * wc + 32 * t + fr) * 64 + kh + fk]);
            }
#pragma unroll
            for (int i = 0; i < 2; ++i)
#pragma unroll
                for (int j = 0; j < 2; ++j)
                    acc[i][j] = __builtin_amdgcn_mfma_f32_32x32x16_bf16(
                        af[i], bf_[j], acc[i][j], 0, 0, 0);
        }
        __syncthreads();
    }

    // C/D layout (m74/m101): col = lane&31, row = (r&3) + 8*(r>>2) + 4*(lane>>5)
    OutT* Cb;
    size_t rstride;
    if constexpr (PANEL) { Cb = C + (size_t)n0 * M; rstride = 128; }
    else                 { Cb = C + n0;             rstride = (size_t)N; }
#pragma unroll
    for (int i = 0; i < 2; ++i)
#pragma unroll
        for (int j = 0; j < 2; ++j)
#pragma unroll
            for (int r = 0; r < 16; ++r) {
                const int rowL = (r & 3) + 8 * (r >> 2) + 4 * (lane >> 5);
                const int rowg = m0 + 64 * wr + 32 * i + rowL;
                const int c    = 64 * wc + 32 * j + (lane & 31);
                float v = acc[i][j][r];
                if constexpr (sizeof(OutT) == 2)
                    Cb[(size_t)rowg * rstride + c] = (OutT)f2bf(v);
                else
                    Cb[(size_t)rowg * rstride + c] = (OutT)v;
            }
}

// ---------------------------------------------------------------------------
// qkv panel layout: qkv_p[ct][row][c], ct = t*8+h (t: 0=q,1=k,2=v),
// row = b*SS+s, c = 0..127. Plane stride = MROWS*128.
// ---------------------------------------------------------------------------
static constexpr size_t PLANE = (size_t)MROWS * 128;

// ---------------------------------------------------------------------------
// Phase A: one packed FFT Z=FFT(k+iv) per position; P = FK*FV via conjugate
// pairing: P[n] = -i*(Z[n]^2 - conj(Z[n']^2))/4, n' = -n. Stores P (bf16
// packed, permuted array-position order) and per-chunk totals (fp32).
// ---------------------------------------------------------------------------
__global__ __launch_bounds__(256) void hrr_phaseA(const unsigned short* __restrict__ qkvp,
                                                  unsigned int* __restrict__ P,
                                                  float* __restrict__ totals)
{
    const int blk = blockIdx.x;
    const int bh = blk / NCHUNK;
    const int chunk = blk % NCHUNK;
    const int b = bh >> 3, h = bh & 7;
    const int tid = threadIdx.x;
    const int wave = tid >> 6, lane = tid & 63;

    cpx tw[7];
    make_tw(lane, tw);
    const int pl0 = pair_lane_even(lane);
    const int pl1 = lane ^ 63;

    const unsigned short* kpl = qkvp + (size_t)(8 + h) * PLANE + (size_t)(b * SS) * 128;
    const unsigned short* vpl = qkvp + (size_t)(16 + h) * PLANE + (size_t)(b * SS) * 128;

    cpx acc0 = {0.f, 0.f}, acc1 = {0.f, 0.f};
    const int s0 = chunk * CS + wave * (CS / 4);
    for (int i = 0; i < CS / 4; ++i) {
        const int s = s0 + i;
        const unsigned short* kr = kpl + (size_t)s * 128;
        const unsigned short* vr = vpl + (size_t)s * 128;
        cpx z0 = { bf2f(kr[lane]),      bf2f(vr[lane]) };
        cpx z1 = { bf2f(kr[64 + lane]), bf2f(vr[64 + lane]) };
        fft128_fwd(z0, z1, tw, lane);
        cpx sq0 = cmul(z0, z0);
        cpx sq1 = cmul(z1, z1);
        cpx sp0 = shfl_at(sq0, pl0);
        cpx sp1 = shfl_at(sq1, pl1);
        cpx p0 = { 0.25f * (sq0.im + sp0.im), 0.25f * (sp0.re - sq0.re) };
        cpx p1 = { 0.25f * (sq1.im + sp1.im), 0.25f * (sp1.re - sq1.re) };
        acc0 = cadd(acc0, p0);
        acc1 = cadd(acc1, p1);
        unsigned int* prow = P + ((size_t)bh * SS + s) * 128;
        prow[lane]      = pack_rne(p0.re, p0.im);
        prow[64 + lane] = pack_rne(p1.re, p1.im);
    }

    __shared__ float red[4][256];
    red[wave][lane * 2 + 0] = acc0.re;
    red[wave][lane * 2 + 1] = acc0.im;
    red[wave][128 + lane * 2 + 0] = acc1.re;
    red[wave][128 + lane * 2 + 1] = acc1.im;
    __syncthreads();

    float s4 = red[0][tid] + red[1][tid] + red[2][tid] + red[3][tid];
    totals[((size_t)bh * NCHUNK + chunk) * 256 + tid] = s4;
}

// ---------------------------------------------------------------------------
// Phase B: exclusive scan of chunk totals over 128 chunks per (bh, comp)
// ---------------------------------------------------------------------------
__global__ __launch_bounds__(256) void hrr_phaseB(float* __restrict__ totals)
{
    const int bh = blockIdx.x;
    const int t = threadIdx.x;
    float run = 0.f;
#pragma unroll 4
    for (int c = 0; c < NCHUNK; ++c) {
        const size_t idx = ((size_t)bh * NCHUNK + c) * 256 + t;
        float v = totals[idx];
        totals[idx] = run;
        run += v;
    }
}

// ---------------------------------------------------------------------------
// Phase C: load P (bf16) -> fp32 LDS, in-chunk scan, then paired unbind:
// Zq = FFT(q1 + i q2); conj(FQ1)=(conjA+B)/2, conj(FQ2)=i(conjA-B)/2 (B = Zq
// at pair lane); U = C1*conjFQ1 + i*C2*conjFQ2; IFFT(U) -> vals1=Re, vals2=Im.
// ---------------------------------------------------------------------------
__global__ __launch_bounds__(256) void hrr_phaseC(const unsigned short* __restrict__ qkvp,
                                                  const unsigned int* __restrict__ P,
                                                  const float* __restrict__ totals,
                                                  unsigned short* __restrict__ vals)
{
    __shared__ float Pf[CS * 256];   // 32 KB

    const int blk = blockIdx.x;
    const int bh = blk / NCHUNK;
    const int chunk = blk % NCHUNK;
    const int b = bh >> 3, h = bh & 7;
    const int tid = threadIdx.x;
    const int wave = tid >> 6, lane = tid & 63;

    cpx tw[7];
    make_tw(lane, tw);
    const int pl0 = pair_lane_even(lane);
    const int pl1 = lane ^ 63;

    // Load P for this chunk into LDS as fp32 (comp = 2p + part)
#pragma unroll
    for (int it = 0; it < CS / 4; ++it) {
        const int sl = it * 4 + wave;
        const int s = chunk * CS + sl;
        const unsigned int* prow = P + ((size_t)bh * SS + s) * 128;
        unsigned int a = prow[lane];
        unsigned int c = prow[64 + lane];
        float2 fa = { bf2f(a), bf2f(a >> 16) };
        float2 fc = { bf2f(c), bf2f(c >> 16) };
        *reinterpret_cast<float2*>(&Pf[sl * 256 + 2 * lane]) = fa;
        *reinterpret_cast<float2*>(&Pf[sl * 256 + 128 + 2 * lane]) = fc;
    }
    __syncthreads();

    // Component-parallel inclusive scan over the chunk
    {
        float run = totals[((size_t)bh * NCHUNK + chunk) * 256 + tid];
#pragma unroll 8
        for (int s = 0; s < CS; ++s) {
            run += Pf[s * 256 + tid];
            Pf[s * 256 + tid] = run;
        }
    }
    __syncthreads();

    const unsigned short* qpl = qkvp + (size_t)h * PLANE + (size_t)(b * SS) * 128;

    // Paired unbind + inverse FFT: wave handles 8 positions = 4 pairs
    for (int i = 0; i < CS / 8; ++i) {
        const int sl = wave * (CS / 4) + 2 * i;
        const int s1 = chunk * CS + sl;
        const unsigned short* b1 = qpl + (size_t)s1 * 128;
        const unsigned short* b2 = b1 + 128;
        cpx z0 = { bf2f(b1[lane]),      bf2f(b2[lane]) };
        cpx z1 = { bf2f(b1[64 + lane]), bf2f(b2[64 + lane]) };
        fft128_fwd(z0, z1, tw, lane);
        cpx B0 = shfl_at(z0, pl0);
        cpx B1 = shfl_at(z1, pl1);
        // conj(FQ1) = (conj A + B)/2 ; conj(FQ2) = i*(conj A - B)/2
        cpx cf1_0 = { 0.5f * (z0.re + B0.re), 0.5f * (B0.im - z0.im) };
        cpx cf1_1 = { 0.5f * (z1.re + B1.re), 0.5f * (B1.im - z1.im) };
        cpx cf2_0 = { 0.5f * (z0.im + B0.im), 0.5f * (z0.re - B0.re) };
        cpx cf2_1 = { 0.5f * (z1.im + B1.im), 0.5f * (z1.re - B1.re) };

        const float* r1 = &Pf[sl * 256];
        const float* r2 = r1 + 256;
        float2 t0 = *reinterpret_cast<const float2*>(&r1[2 * lane]);
        float2 t1 = *reinterpret_cast<const float2*>(&r1[128 + 2 * lane]);
        float2 t2 = *reinterpret_cast<const float2*>(&r2[2 * lane]);
        float2 t3 = *reinterpret_cast<const float2*>(&r2[128 + 2 * lane]);
        cpx C1_0 = { t0.x, t0.y }, C1_1 = { t1.x, t1.y };
        cpx C2_0 = { t2.x, t2.y }, C2_1 = { t3.x, t3.y };

        cpx a0 = cmul(C1_0, cf1_0), w0 = cmul(C2_0, cf2_0);
        cpx a1 = cmul(C1_1, cf1_1), w1 = cmul(C2_1, cf2_1);
        cpx u0 = { a0.re - w0.im, a0.im + w0.re };   // a + i*w
        cpx u1 = { a1.re - w1.im, a1.im + w1.re };
        fft128_inv(u0, u1, tw, lane);

        unsigned short* o1 = vals + (size_t)(b * SS + s1) * DD + h * 128;
        unsigned short* o2 = o1 + DD;
        o1[lane]      = f2bf(u0.re);
        o1[64 + lane] = f2bf(u1.re);
        o2[lane]      = f2bf(u0.im);
        o2[64 + lane] = f2bf(u1.im);
    }
}

// ---------------------------------------------------------------------------
// Launch
// ---------------------------------------------------------------------------
extern "C" void kernel_launch(void* const* d_in, const int* in_sizes, int n_in,
                              void* d_out, int out_size, void* d_ws, size_t ws_size,
                              hipStream_t stream) {
    const float* x     = (const float*)d_in[0];   // [B,S,D]
    const float* w_qkv = (const float*)d_in[1];   // [D, 3D]
    const float* w_out = (const float*)d_in[2];   // [D, D]
    float* out = (float*)d_out;                   // [B,S,D]

    // Workspace layout (~247.5 MB total):
    //   qkv    bf16 [24][16384][128] (panel) 100.7 MB
    //   xb     bf16 [16384,1024]              33.6 MB
    //   vals   bf16 [16384,1024]              33.6 MB
    //   P      uint [32,4096,128]             67.1 MB  (bf16 re,im packed)
    //   totals fp32 [32,128,256]               4.2 MB
    //   wqkvt  bf16 [3072,1024]                6.3 MB
    //   woutt  bf16 [1024,1024]                2.1 MB
    unsigned short* qkv  = (unsigned short*)d_ws;
    unsigned short* xb   = qkv + (size_t)MROWS * 3072;
    unsigned short* vals = xb + (size_t)MROWS * DD;
    unsigned int* P      = (unsigned int*)(vals + (size_t)MROWS * DD);
    float* totals        = (float*)(P + (size_t)32 * SS * 128);
    unsigned short* wqkvt = (unsigned short*)(totals + (size_t)32 * NCHUNK * 256);
    unsigned short* woutt = wqkvt + (size_t)3072 * 1024;

    // 0) input prep
    convert_bf16<<<(MROWS * DD) / (256 * 8), 256, 0, stream>>>(x, xb);
    transpose_rn<<<dim3(3072 / 32, 1024 / 32), 256, 0, stream>>>(w_qkv, wqkvt, 1024, 3072);
    transpose_rn<<<dim3(1024 / 32, 1024 / 32), 256, 0, stream>>>(w_out, woutt, 1024, 1024);

    // 1) qkv = x @ w_qkv  (panel output: [ct][row][128], ct = t*8+h)
    gemm_bt32<unsigned short, true><<<dim3(3072 / 128, MROWS / 128), 256, 0, stream>>>(
        xb, wqkvt, qkv, MROWS, 3072, DD);

    // 2) packed FFT -> P + chunk totals
    hrr_phaseA<<<BB * HH * NCHUNK, 256, 0, stream>>>(qkv, P, totals);

    // 3) exclusive scan of chunk totals
    hrr_phaseB<<<BB * HH, 256, 0, stream>>>(totals);

    // 4) scan P in-chunk + paired unbind + IFFT -> vals
    hrr_phaseC<<<BB * HH * NCHUNK, 256, 0, stream>>>(qkv, P, totals, vals);

    // 5) out = vals @ w_out  (standard row-major output)
    gemm_bt32<float, false><<<dim3(DD / 128, MROWS / 128), 256, 0, stream>>>(
        vals, woutt, out, MROWS, DD, DD);
}